// Round 4
// baseline (1008.986 us; speedup 1.0000x reference)
//
#include <hip/hip_runtime.h>
#include <stdint.h>

typedef __attribute__((ext_vector_type(8))) short  short8;
typedef __attribute__((ext_vector_type(4))) float  f32x4;

static __device__ __forceinline__ uint16_t f2bf(float x) {
    union { float f; uint32_t u; } v; v.f = x;
    return (uint16_t)((v.u + 0x7FFFu + ((v.u >> 16) & 1u)) >> 16);
}

// ---------------- kernel 0: W2 -> fp32 permuted W2p[f][d*32+c] = W2[f][c*32+d]
__global__ __launch_bounds__(256) void prep_w2(const float* __restrict__ W2,
                                               float* __restrict__ W2p) {
    int idx = blockIdx.x * 256 + threadIdx.x;   // 0..131071
    int f  = idx >> 10;
    int kd = idx & 1023;
    int d = kd >> 5, c = kd & 31;
    W2p[idx] = W2[f * 1024 + c * 32 + d];
}

// ---------------- kernel 1: LayerNorm + proj -> At[(i*32+c)][r], Bt[(j*32+d)][r] (bf16)
__global__ __launch_bounds__(256) void ln_proj(
    const float* __restrict__ mI, const float* __restrict__ lnw,
    const float* __restrict__ lnb, const float* __restrict__ W1,
    const float* __restrict__ b1,
    uint16_t* __restrict__ At, uint16_t* __restrict__ Bt)
{
    __shared__ float W1s[64 * 129];   // +1 pad
    __shared__ float mns[4][128];
    int t = threadIdx.x;
    for (int idx = t; idx < 64 * 128; idx += 256)
        W1s[(idx >> 7) * 129 + (idx & 127)] = W1[idx];

    int w = t >> 6, l = t & 63;
    int rid = blockIdx.x * 4 + w;     // rid = r*256 + i  (m is [b][r][L][IN])
    int r = rid >> 8, i = rid & 255;
    const float* row = mI + (size_t)rid * 128;
    float2 xv = *(const float2*)(row + 2 * l);
    float x0 = xv.x, x1 = xv.y;
    float s = x0 + x1, ss = x0 * x0 + x1 * x1;
    #pragma unroll
    for (int off = 32; off > 0; off >>= 1) {
        s  += __shfl_xor(s, off);
        ss += __shfl_xor(ss, off);
    }
    float mean = s * (1.0f / 128.0f);
    float var  = ss * (1.0f / 128.0f) - mean * mean;
    float rstd = rsqrtf(var + 1e-5f);
    mns[w][2 * l]     = (x0 - mean) * rstd * lnw[2 * l]     + lnb[2 * l];
    mns[w][2 * l + 1] = (x1 - mean) * rstd * lnw[2 * l + 1] + lnb[2 * l + 1];
    __syncthreads();

    float acc = b1[l];
    #pragma unroll 8
    for (int c = 0; c < 128; ++c)
        acc = fmaf(mns[w][c], W1s[l * 129 + c], acc);
    uint16_t hb = f2bf(acc);
    if (l < 32) At[(size_t)(i * 32 + l) * 128 + r]        = hb;
    else        Bt[(size_t)(i * 32 + (l - 32)) * 128 + r] = hb;
}

// ---------------- kernel 2: fused OPM GEMM (MFMA bf16) + fp32 VALU W2 epilogue
// Grid (64,64): block (bx,by) covers i in [by*4,by*4+4), j in [bx*4,bx*4+4)
// Main: C[128ic][128jd] = sum_r At*Bt  (4 waves, 64x64 each)
// LDS:  Out[p=16][kd, stride 1028] fp32 (UNswizzled), Out = C/128, kd = d*32+c
// Epi:  z[f][p] = sum_kd W2p[f][kd]*Out[p][kd] + b2[f]   (pure VALU fp32)
__global__ __launch_bounds__(256) void fused_opm(
    const uint16_t* __restrict__ At, const uint16_t* __restrict__ Bt,
    const float* __restrict__ W2p, const float* __restrict__ b2,
    float* __restrict__ z)
{
    __shared__ __align__(16) float outl[16 * 1028];  // 64.25 KB, +4 pad per row
    const int t = threadIdx.x;
    const int w = t >> 6, l = t & 63;
    const int l16 = l & 15, lh = l >> 4;
    const int bx = blockIdx.x, by = blockIdx.y;
    const int wm = w >> 1, wn = w & 1;

    // ---- main GEMM ----
    f32x4 acc[4][4];
    #pragma unroll
    for (int a = 0; a < 4; ++a)
        #pragma unroll
        for (int b = 0; b < 4; ++b) acc[a][b] = (f32x4)(0.0f);

    const uint16_t* Abase = At + (size_t)(by * 128 + wm * 64 + l16) * 128 + lh * 8;
    const uint16_t* Bbase = Bt + (size_t)(bx * 128 + wn * 64 + l16) * 128 + lh * 8;
    #pragma unroll
    for (int ks = 0; ks < 4; ++ks) {
        short8 af[4], bf[4];
        #pragma unroll
        for (int mt = 0; mt < 4; ++mt)
            af[mt] = *(const short8*)(Abase + mt * 16 * 128 + ks * 32);
        #pragma unroll
        for (int nt = 0; nt < 4; ++nt)
            bf[nt] = *(const short8*)(Bbase + nt * 16 * 128 + ks * 32);
        #pragma unroll
        for (int mt = 0; mt < 4; ++mt)
            #pragma unroll
            for (int nt = 0; nt < 4; ++nt)
                acc[mt][nt] = __builtin_amdgcn_mfma_f32_16x16x32_bf16(
                    af[mt], bf[nt], acc[mt][nt], 0, 0, 0);
    }

    // ---- C/128 -> fp32 LDS Out[p][kd], kd = d*32+c (no swizzle; float4 stores) ----
    // C/D layout (m89): reg v of acc[mt][nt] = C[row = wm*64+mt*16+lh*4+v][col = wn*64+nt*16+l16]
    #pragma unroll
    for (int mt = 0; mt < 4; ++mt) {
        int pi = wm * 2 + (mt >> 1);
        int c0 = (mt & 1) * 16 + lh * 4;        // (wm*64+mt*16+lh*4) & 31, 4-aligned
        #pragma unroll
        for (int nt = 0; nt < 4; ++nt) {
            int pj = wn * 2 + (nt >> 1);
            int d  = (nt & 1) * 16 + l16;       // (wn*64+nt*16+l16) & 31
            int p  = pi * 4 + pj;
            f32x4 v = acc[mt][nt];
            float4 vv;
            vv.x = v[0] * (1.0f / 128.0f);
            vv.y = v[1] * (1.0f / 128.0f);
            vv.z = v[2] * (1.0f / 128.0f);
            vv.w = v[3] * (1.0f / 128.0f);
            *(float4*)&outl[p * 1028 + d * 32 + c0] = vv;
        }
    }
    __syncthreads();

    // ---- epilogue: thread owns (p = t&15, f-octet = t>>4), pure fp32 VALU ----
    const int p  = t & 15;
    const int f0 = (t >> 4) * 8;
    float za[8] = {0.f, 0.f, 0.f, 0.f, 0.f, 0.f, 0.f, 0.f};
    const float* Wr = W2p + (size_t)f0 * 1024;
    const float* Orow = &outl[p * 1028];
    for (int kd = 0; kd < 1024; kd += 4) {
        float4 o = *(const float4*)(Orow + kd);
        #pragma unroll
        for (int ff = 0; ff < 8; ++ff) {
            float4 wv = *(const float4*)(Wr + ff * 1024 + kd);
            za[ff] = fmaf(o.x, wv.x, za[ff]);
            za[ff] = fmaf(o.y, wv.y, za[ff]);
            za[ff] = fmaf(o.z, wv.z, za[ff]);
            za[ff] = fmaf(o.w, wv.w, za[ff]);
        }
    }
    const int zi = by * 4 + (p >> 2);
    const int zj = bx * 4 + (p & 3);
    float* zrow = z + ((size_t)zi * 256 + zj) * 128 + f0;
    float4 s0, s1;
    s0.x = za[0] + b2[f0 + 0]; s0.y = za[1] + b2[f0 + 1];
    s0.z = za[2] + b2[f0 + 2]; s0.w = za[3] + b2[f0 + 3];
    s1.x = za[4] + b2[f0 + 4]; s1.y = za[5] + b2[f0 + 5];
    s1.z = za[6] + b2[f0 + 6]; s1.w = za[7] + b2[f0 + 7];
    *(float4*)(zrow)     = s0;
    *(float4*)(zrow + 4) = s1;
}

extern "C" void kernel_launch(void* const* d_in, const int* in_sizes, int n_in,
                              void* d_out, int out_size, void* d_ws, size_t ws_size,
                              hipStream_t stream) {
    const float* m_in = (const float*)d_in[0];
    const float* ln_w = (const float*)d_in[1];
    const float* ln_b = (const float*)d_in[2];
    const float* W1   = (const float*)d_in[3];
    const float* b1   = (const float*)d_in[4];
    const float* W2   = (const float*)d_in[5];
    const float* b2   = (const float*)d_in[6];
    float* z = (float*)d_out;

    uint16_t* At    = (uint16_t*)d_ws;                          // 2 MB
    uint16_t* Bt    = At + 8192 * 128;                          // 2 MB
    float*    W2p32 = (float*)((char*)d_ws + 4 * 1024 * 1024);  // 512 KB

    prep_w2<<<512, 256, 0, stream>>>(W2, W2p32);
    ln_proj<<<8192, 256, 0, stream>>>(m_in, ln_w, ln_b, W1, b1, At, Bt);
    fused_opm<<<dim3(64, 64), 256, 0, stream>>>(At, Bt, W2p32, b2, z);
}

// Round 5
// 220.150 us; speedup vs baseline: 4.5832x; 4.5832x over previous
//
#include <hip/hip_runtime.h>
#include <stdint.h>

typedef __attribute__((ext_vector_type(8))) short  short8;
typedef __attribute__((ext_vector_type(4))) float  f32x4;

static __device__ __forceinline__ uint16_t f2bf(float x) {
    union { float f; uint32_t u; } v; v.f = x;
    return (uint16_t)((v.u + 0x7FFFu + ((v.u >> 16) & 1u)) >> 16);
}

// ---------------- kernel 0: W2 -> bf16 permuted W2p[f][d*32+c] = W2[f][c*32+d]
__global__ __launch_bounds__(256) void prep_w2(const float* __restrict__ W2,
                                               uint16_t* __restrict__ W2p) {
    int idx = blockIdx.x * 256 + threadIdx.x;   // 0..131071
    int f  = idx >> 10;
    int kd = idx & 1023;
    int d = kd >> 5, c = kd & 31;
    W2p[idx] = f2bf(W2[f * 1024 + c * 32 + d]);
}

// ---------------- kernel 1: LayerNorm + proj -> At[(i*32+c)][r], Bt[(j*32+d)][r] (bf16)
__global__ __launch_bounds__(256) void ln_proj(
    const float* __restrict__ mI, const float* __restrict__ lnw,
    const float* __restrict__ lnb, const float* __restrict__ W1,
    const float* __restrict__ b1,
    uint16_t* __restrict__ At, uint16_t* __restrict__ Bt)
{
    __shared__ float W1s[64 * 129];   // +1 pad
    __shared__ float mns[4][128];
    int t = threadIdx.x;
    for (int idx = t; idx < 64 * 128; idx += 256)
        W1s[(idx >> 7) * 129 + (idx & 127)] = W1[idx];

    int w = t >> 6, l = t & 63;
    int rid = blockIdx.x * 4 + w;     // rid = r*256 + i  (m is [b][r][L][IN])
    int r = rid >> 8, i = rid & 255;
    const float* row = mI + (size_t)rid * 128;
    float2 xv = *(const float2*)(row + 2 * l);
    float x0 = xv.x, x1 = xv.y;
    float s = x0 + x1, ss = x0 * x0 + x1 * x1;
    #pragma unroll
    for (int off = 32; off > 0; off >>= 1) {
        s  += __shfl_xor(s, off);
        ss += __shfl_xor(ss, off);
    }
    float mean = s * (1.0f / 128.0f);
    float var  = ss * (1.0f / 128.0f) - mean * mean;
    float rstd = rsqrtf(var + 1e-5f);
    mns[w][2 * l]     = (x0 - mean) * rstd * lnw[2 * l]     + lnb[2 * l];
    mns[w][2 * l + 1] = (x1 - mean) * rstd * lnw[2 * l + 1] + lnb[2 * l + 1];
    __syncthreads();

    float acc = b1[l];
    #pragma unroll 8
    for (int c = 0; c < 128; ++c)
        acc = fmaf(mns[w][c], W1s[l * 129 + c], acc);
    uint16_t hb = f2bf(acc);
    if (l < 32) At[(size_t)(i * 32 + l) * 128 + r]        = hb;
    else        Bt[(size_t)(i * 32 + (l - 32)) * 128 + r] = hb;
}

// ---------------- kernel 2: fused OPM GEMM (MFMA bf16) + MFMA W2 epilogue
// Grid (64,64): block (bx,by) covers i in [by*4,by*4+4), j in [bx*4,bx*4+4)
// Main: C[128ic][128jd] = sum_r At*Bt  (4 waves, 64x64 each)
// LDS:  Out[p=16][kd, stride 1032] bf16 (PADDED, no swizzle), Out = C/128, kd = d*32+c
// Epi:  Z[f=128][p=16] = W2p(128x1024) x Out(1024x16) via MFMA; z += b2
__global__ __launch_bounds__(256) void fused_opm(
    const uint16_t* __restrict__ At, const uint16_t* __restrict__ Bt,
    const uint16_t* __restrict__ W2p, const float* __restrict__ b2,
    float* __restrict__ z)
{
    __shared__ __align__(16) uint16_t outl[16 * 1032];  // 33 KB, +8 shorts pad per row
    const int t = threadIdx.x;
    const int w = t >> 6, l = t & 63;
    const int l16 = l & 15, lh = l >> 4;
    const int bx = blockIdx.x, by = blockIdx.y;
    const int wm = w >> 1, wn = w & 1;

    // ---- main GEMM (unchanged, proven) ----
    f32x4 acc[4][4];
    #pragma unroll
    for (int a = 0; a < 4; ++a)
        #pragma unroll
        for (int b = 0; b < 4; ++b) acc[a][b] = (f32x4)(0.0f);

    const uint16_t* Abase = At + (size_t)(by * 128 + wm * 64 + l16) * 128 + lh * 8;
    const uint16_t* Bbase = Bt + (size_t)(bx * 128 + wn * 64 + l16) * 128 + lh * 8;
    #pragma unroll
    for (int ks = 0; ks < 4; ++ks) {
        short8 af[4], bf[4];
        #pragma unroll
        for (int mt = 0; mt < 4; ++mt)
            af[mt] = *(const short8*)(Abase + mt * 16 * 128 + ks * 32);
        #pragma unroll
        for (int nt = 0; nt < 4; ++nt)
            bf[nt] = *(const short8*)(Bbase + nt * 16 * 128 + ks * 32);
        #pragma unroll
        for (int mt = 0; mt < 4; ++mt)
            #pragma unroll
            for (int nt = 0; nt < 4; ++nt)
                acc[mt][nt] = __builtin_amdgcn_mfma_f32_16x16x32_bf16(
                    af[mt], bf[nt], acc[mt][nt], 0, 0, 0);
    }

    // ---- C/128 -> bf16 -> Out_lds[p][kd] (padded stride 1032, NO swizzle) ----
    // C/D layout (proven in R4-pass): reg v of acc[mt][nt] =
    //   C[row = wm*64+mt*16+lh*4+v][col = wn*64+nt*16+l16]
    #pragma unroll
    for (int mt = 0; mt < 4; ++mt) {
        int pi = wm * 2 + (mt >> 1);
        int c0 = (mt & 1) * 16 + lh * 4;
        #pragma unroll
        for (int nt = 0; nt < 4; ++nt) {
            int pj = wn * 2 + (nt >> 1);
            int d  = (nt & 1) * 16 + l16;
            int p  = pi * 4 + pj;
            f32x4 v = acc[mt][nt];
            uint32_t u0 = (uint32_t)f2bf(v[0] * (1.0f / 128.0f)) |
                          ((uint32_t)f2bf(v[1] * (1.0f / 128.0f)) << 16);
            uint32_t u1 = (uint32_t)f2bf(v[2] * (1.0f / 128.0f)) |
                          ((uint32_t)f2bf(v[3] * (1.0f / 128.0f)) << 16);
            uint2 pk; pk.x = u0; pk.y = u1;
            *(uint2*)&outl[p * 1032 + d * 32 + c0] = pk;   // 8B aligned
        }
    }
    __syncthreads();

    // ---- epilogue: Z[f][p] = W2p x Out via MFMA ----
    f32x4 zacc[2];
    zacc[0] = (f32x4)(0.0f);
    zacc[1] = (f32x4)(0.0f);
    const uint16_t* Wb0 = W2p + (size_t)((2 * w) * 16 + l16) * 1024 + lh * 8;
    const uint16_t* Wb1 = W2p + (size_t)((2 * w + 1) * 16 + l16) * 1024 + lh * 8;
    const uint16_t* Ob  = &outl[l16 * 1032 + lh * 8];
    #pragma unroll 4
    for (int ks = 0; ks < 32; ++ks) {
        short8 ofrag = *(const short8*)(Ob  + ks * 32);
        short8 w0    = *(const short8*)(Wb0 + ks * 32);
        short8 w1    = *(const short8*)(Wb1 + ks * 32);
        zacc[0] = __builtin_amdgcn_mfma_f32_16x16x32_bf16(w0, ofrag, zacc[0], 0, 0, 0);
        zacc[1] = __builtin_amdgcn_mfma_f32_16x16x32_bf16(w1, ofrag, zacc[1], 0, 0, 0);
    }

    // ---- write z (fp32): lane has p=l16, rows lh*4+j of each 16-f tile ----
    const int p  = l16;
    const int zi = by * 4 + (p >> 2);
    const int zj = bx * 4 + (p & 3);
    float* zrow = z + ((size_t)zi * 256 + zj) * 128;
    #pragma unroll
    for (int ft = 0; ft < 2; ++ft) {
        int f0 = (2 * w + ft) * 16 + lh * 4;
        float4 zr;
        zr.x = zacc[ft][0] + b2[f0 + 0];
        zr.y = zacc[ft][1] + b2[f0 + 1];
        zr.z = zacc[ft][2] + b2[f0 + 2];
        zr.w = zacc[ft][3] + b2[f0 + 3];
        *(float4*)(zrow + f0) = zr;
    }
}

extern "C" void kernel_launch(void* const* d_in, const int* in_sizes, int n_in,
                              void* d_out, int out_size, void* d_ws, size_t ws_size,
                              hipStream_t stream) {
    const float* m_in = (const float*)d_in[0];
    const float* ln_w = (const float*)d_in[1];
    const float* ln_b = (const float*)d_in[2];
    const float* W1   = (const float*)d_in[3];
    const float* b1   = (const float*)d_in[4];
    const float* W2   = (const float*)d_in[5];
    const float* b2   = (const float*)d_in[6];
    float* z = (float*)d_out;

    uint16_t* At  = (uint16_t*)d_ws;                 // 2 MB
    uint16_t* Bt  = At + 8192 * 128;                 // 2 MB
    uint16_t* W2p = Bt + 8192 * 128;                 // 256 KB

    prep_w2<<<512, 256, 0, stream>>>(W2, W2p);
    ln_proj<<<8192, 256, 0, stream>>>(m_in, ln_w, ln_b, W1, b1, At, Bt);
    fused_opm<<<dim3(64, 64), 256, 0, stream>>>(At, Bt, W2p, b2, z);
}

// Round 6
// 107.736 us; speedup vs baseline: 9.3654x; 2.0434x over previous
//
#include <hip/hip_runtime.h>
#include <stdint.h>

typedef __attribute__((ext_vector_type(8))) short  short8;
typedef __attribute__((ext_vector_type(4))) float  f32x4;

static __device__ __forceinline__ uint16_t f2bf(float x) {
    union { float f; uint32_t u; } v; v.f = x;
    return (uint16_t)((v.u + 0x7FFFu + ((v.u >> 16) & 1u)) >> 16);
}

// Fragment-order layout for a 16x32 bf16 MFMA operand tile:
//   frag[(tile*NKS + ks)*512 + lane*8 + e]  where lane = row16 + 16*kh, k = ks*32 + kh*8 + e
// A wave's fragment load is then one contiguous 1KB read.

// ---------------- kernel 0: W2 -> bf16 fragment-order W2f
// W2 tile grid: ftile = f>>4 (8 tiles), ks = kd>>5 (32 tiles), kd = d*32+c
__global__ __launch_bounds__(256) void prep_w2(const float* __restrict__ W2,
                                               uint16_t* __restrict__ W2f) {
    int idx = blockIdx.x * 256 + threadIdx.x;   // 0..131071
    int f  = idx >> 10;
    int kd = idx & 1023;
    int d = kd >> 5, c = kd & 31;
    int ftile = f >> 4, l16 = f & 15;
    int ks = kd >> 5, kh = (kd >> 3) & 3, e = kd & 7;
    int lane = l16 + 16 * kh;
    W2f[(size_t)(ftile * 32 + ks) * 512 + lane * 8 + e] = f2bf(W2[f * 1024 + c * 32 + d]);
}

// ---------------- kernel 1: LayerNorm + proj -> At/Bt in fragment order (bf16)
// A row index = i*32+cc (cc=c), tile mtile = i*2 + (cc>>4), NKS = 4 (K=128=r)
__global__ __launch_bounds__(256) void ln_proj(
    const float* __restrict__ mI, const float* __restrict__ lnw,
    const float* __restrict__ lnb, const float* __restrict__ W1,
    const float* __restrict__ b1,
    uint16_t* __restrict__ At, uint16_t* __restrict__ Bt)
{
    __shared__ float W1s[64 * 129];   // +1 pad
    __shared__ float mns[4][128];
    int t = threadIdx.x;
    for (int idx = t; idx < 64 * 128; idx += 256)
        W1s[(idx >> 7) * 129 + (idx & 127)] = W1[idx];

    int w = t >> 6, l = t & 63;
    int rid = blockIdx.x * 4 + w;     // rid = r*256 + i  (m is [b][r][L][IN])
    int r = rid >> 8, i = rid & 255;
    const float* row = mI + (size_t)rid * 128;
    float2 xv = *(const float2*)(row + 2 * l);
    float x0 = xv.x, x1 = xv.y;
    float s = x0 + x1, ss = x0 * x0 + x1 * x1;
    #pragma unroll
    for (int off = 32; off > 0; off >>= 1) {
        s  += __shfl_xor(s, off);
        ss += __shfl_xor(ss, off);
    }
    float mean = s * (1.0f / 128.0f);
    float var  = ss * (1.0f / 128.0f) - mean * mean;
    float rstd = rsqrtf(var + 1e-5f);
    mns[w][2 * l]     = (x0 - mean) * rstd * lnw[2 * l]     + lnb[2 * l];
    mns[w][2 * l + 1] = (x1 - mean) * rstd * lnw[2 * l + 1] + lnb[2 * l + 1];
    __syncthreads();

    float acc = b1[l];
    #pragma unroll 8
    for (int c = 0; c < 128; ++c)
        acc = fmaf(mns[w][c], W1s[l * 129 + c], acc);
    uint16_t hb = f2bf(acc);

    int cc = l & 31;
    int mtile = i * 2 + (cc >> 4);
    int lane  = (cc & 15) + 16 * ((r >> 3) & 3);
    size_t addr = (size_t)(mtile * 4 + (r >> 5)) * 512 + lane * 8 + (r & 7);
    if (l < 32) At[addr] = hb;
    else        Bt[addr] = hb;
}

// ---------------- kernel 2: fused OPM GEMM (MFMA bf16) + MFMA W2 epilogue
// Grid (64,64): block (bx,by) covers i in [by*4,by*4+4), j in [bx*4,bx*4+4)
// Main: C[128ic][128jd] = sum_r At*Bt  (4 waves, 64x64 each), frags direct from global
// LDS:  Out[p=16][kd, stride 1032] bf16 (padded), Out = C/128, kd = d*32+c
// Epi:  Z[f=128][p=16] = W2f x Out via MFMA; z += b2
__global__ __launch_bounds__(256, 4) void fused_opm(
    const uint16_t* __restrict__ At, const uint16_t* __restrict__ Bt,
    const uint16_t* __restrict__ W2f, const float* __restrict__ b2,
    float* __restrict__ z)
{
    __shared__ __align__(16) uint16_t outl[16 * 1032];  // 33 KB
    const int t = threadIdx.x;
    const int w = t >> 6, l = t & 63;
    const int l16 = l & 15, lh = l >> 4;
    const int bx = blockIdx.x, by = blockIdx.y;
    const int wm = w >> 1, wn = w & 1;

    // ---- main GEMM: fragment loads are contiguous 1KB/wave ----
    f32x4 acc[4][4];
    #pragma unroll
    for (int a = 0; a < 4; ++a)
        #pragma unroll
        for (int b = 0; b < 4; ++b) acc[a][b] = (f32x4)(0.0f);

    const uint16_t* Abase = At + (size_t)(by * 8 + wm * 4) * 4 * 512 + l * 8;
    const uint16_t* Bbase = Bt + (size_t)(bx * 8 + wn * 4) * 4 * 512 + l * 8;
    #pragma unroll
    for (int ks = 0; ks < 4; ++ks) {
        short8 af[4], bf[4];
        #pragma unroll
        for (int mt = 0; mt < 4; ++mt)
            af[mt] = *(const short8*)(Abase + (size_t)(mt * 4 + ks) * 512);
        #pragma unroll
        for (int nt = 0; nt < 4; ++nt)
            bf[nt] = *(const short8*)(Bbase + (size_t)(nt * 4 + ks) * 512);
        #pragma unroll
        for (int mt = 0; mt < 4; ++mt)
            #pragma unroll
            for (int nt = 0; nt < 4; ++nt)
                acc[mt][nt] = __builtin_amdgcn_mfma_f32_16x16x32_bf16(
                    af[mt], bf[nt], acc[mt][nt], 0, 0, 0);
    }

    // ---- C/128 -> bf16 -> Out_lds[p][kd] (padded stride 1032) ----
    // reg v of acc[mt][nt] = C[row = wm*64+mt*16+lh*4+v][col = wn*64+nt*16+l16]
    #pragma unroll
    for (int mt = 0; mt < 4; ++mt) {
        int pi = wm * 2 + (mt >> 1);
        int c0 = (mt & 1) * 16 + lh * 4;
        #pragma unroll
        for (int nt = 0; nt < 4; ++nt) {
            int pj = wn * 2 + (nt >> 1);
            int d  = (nt & 1) * 16 + l16;
            int p  = pi * 4 + pj;
            f32x4 v = acc[mt][nt];
            uint32_t u0 = (uint32_t)f2bf(v[0] * (1.0f / 128.0f)) |
                          ((uint32_t)f2bf(v[1] * (1.0f / 128.0f)) << 16);
            uint32_t u1 = (uint32_t)f2bf(v[2] * (1.0f / 128.0f)) |
                          ((uint32_t)f2bf(v[3] * (1.0f / 128.0f)) << 16);
            uint2 pk; pk.x = u0; pk.y = u1;
            *(uint2*)&outl[p * 1032 + d * 32 + c0] = pk;
        }
    }
    __syncthreads();

    // ---- epilogue: Z[f][p] = W2f x Out via MFMA, even/odd split chains + prefetch ----
    f32x4 zacc[2][2];   // [ft][parity]
    #pragma unroll
    for (int a = 0; a < 2; ++a) { zacc[a][0] = (f32x4)(0.0f); zacc[a][1] = (f32x4)(0.0f); }
    const uint16_t* Wt0 = W2f + (size_t)(2 * w)     * 32 * 512 + l * 8;
    const uint16_t* Wt1 = W2f + (size_t)(2 * w + 1) * 32 * 512 + l * 8;
    const uint16_t* Ob  = &outl[l16 * 1032 + lh * 8];

    short8 cw0 = *(const short8*)(Wt0);
    short8 cw1 = *(const short8*)(Wt1);
    #pragma unroll 8
    for (int ks = 0; ks < 32; ++ks) {
        short8 nw0, nw1;
        if (ks < 31) {
            nw0 = *(const short8*)(Wt0 + (size_t)(ks + 1) * 512);
            nw1 = *(const short8*)(Wt1 + (size_t)(ks + 1) * 512);
        }
        short8 ofrag = *(const short8*)(Ob + ks * 32);
        zacc[0][ks & 1] = __builtin_amdgcn_mfma_f32_16x16x32_bf16(cw0, ofrag, zacc[0][ks & 1], 0, 0, 0);
        zacc[1][ks & 1] = __builtin_amdgcn_mfma_f32_16x16x32_bf16(cw1, ofrag, zacc[1][ks & 1], 0, 0, 0);
        cw0 = nw0; cw1 = nw1;
    }

    // ---- write z (fp32): lane has p=l16, rows lh*4+j of each 16-f tile ----
    const int p  = l16;
    const int zi = by * 4 + (p >> 2);
    const int zj = bx * 4 + (p & 3);
    float* zrow = z + ((size_t)zi * 256 + zj) * 128;
    #pragma unroll
    for (int ft = 0; ft < 2; ++ft) {
        int f0 = (2 * w + ft) * 16 + lh * 4;
        float4 zr;
        zr.x = zacc[ft][0][0] + zacc[ft][1][0] + b2[f0 + 0];
        zr.y = zacc[ft][0][1] + zacc[ft][1][1] + b2[f0 + 1];
        zr.z = zacc[ft][0][2] + zacc[ft][1][2] + b2[f0 + 2];
        zr.w = zacc[ft][0][3] + zacc[ft][1][3] + b2[f0 + 3];
        *(float4*)(zrow + f0) = zr;
    }
}

extern "C" void kernel_launch(void* const* d_in, const int* in_sizes, int n_in,
                              void* d_out, int out_size, void* d_ws, size_t ws_size,
                              hipStream_t stream) {
    const float* m_in = (const float*)d_in[0];
    const float* ln_w = (const float*)d_in[1];
    const float* ln_b = (const float*)d_in[2];
    const float* W1   = (const float*)d_in[3];
    const float* b1   = (const float*)d_in[4];
    const float* W2   = (const float*)d_in[5];
    const float* b2   = (const float*)d_in[6];
    float* z = (float*)d_out;

    uint16_t* At  = (uint16_t*)d_ws;                 // 2 MB
    uint16_t* Bt  = At + 8192 * 128;                 // 2 MB
    uint16_t* W2f = Bt + 8192 * 128;                 // 256 KB

    prep_w2<<<512, 256, 0, stream>>>(W2, W2f);
    ln_proj<<<8192, 256, 0, stream>>>(m_in, ln_w, ln_b, W1, b1, At, Bt);
    fused_opm<<<dim3(64, 64), 256, 0, stream>>>(At, Bt, W2f, b2, z);
}

// Round 7
// 71.974 us; speedup vs baseline: 14.0188x; 1.4969x over previous
//
#include <hip/hip_runtime.h>
#include <stdint.h>

typedef __attribute__((ext_vector_type(8))) short  short8;
typedef __attribute__((ext_vector_type(4))) float  f32x4;

static __device__ __forceinline__ uint16_t f2bf(float x) {
    union { float f; uint32_t u; } v; v.f = x;
    return (uint16_t)((v.u + 0x7FFFu + ((v.u >> 16) & 1u)) >> 16);
}

// Fragment-order layout for a 16x32 bf16 MFMA operand tile:
//   frag[(tile*NKS + ks)*512 + lane*8 + e]  where lane = row16 + 16*kh, k = ks*32 + kh*8 + e

// ---------------- kernel 0: weights prep
// blocks [0,512): W2f fragment-order (f-tiles of 16, kd = d*32+c, 32 ks)
// blocks [512,544): W1f fragment-order (f-tiles of 16, c = k, 4 ks)
__global__ __launch_bounds__(256) void prep_weights(
    const float* __restrict__ W2, const float* __restrict__ W1,
    uint16_t* __restrict__ W2f, uint16_t* __restrict__ W1f) {
    int bid = blockIdx.x, t = threadIdx.x;
    if (bid < 512) {
        int idx = bid * 256 + t;              // 0..131071
        int f  = idx >> 10;
        int kd = idx & 1023;
        int d = kd >> 5, c = kd & 31;
        int ftile = f >> 4, l16 = f & 15;
        int ks = kd >> 5, kh = (kd >> 3) & 3, e = kd & 7;
        W2f[(size_t)(ftile * 32 + ks) * 512 + (l16 + 16 * kh) * 8 + e] =
            f2bf(W2[f * 1024 + c * 32 + d]);
    } else {
        int idx = (bid - 512) * 256 + t;      // 0..8191
        int f = idx >> 7, c = idx & 127;
        int ftile = f >> 4, l16 = f & 15;
        int ks = c >> 5, kh = (c >> 3) & 3, e = c & 7;
        W1f[(size_t)(ftile * 4 + ks) * 512 + (l16 + 16 * kh) * 8 + e] =
            f2bf(W1[f * 128 + c]);
    }
}

// ---------------- kernel 1: LayerNorm + proj via MFMA -> At/Bt fragment order
// Block = 16 consecutive rids (fixed r, 16 consecutive i). 256 thr.
__global__ __launch_bounds__(256) void ln_proj(
    const float* __restrict__ mI, const float* __restrict__ lnw,
    const float* __restrict__ lnb, const uint16_t* __restrict__ W1f,
    const float* __restrict__ b1,
    uint16_t* __restrict__ At, uint16_t* __restrict__ Bt)
{
    __shared__ __align__(16) uint16_t mns[256 * 8];   // 4 KB, granule-swizzled
    const int t = threadIdx.x;
    const int bid = blockIdx.x;
    const int i0 = (bid * 16) & 255;
    const int r  = bid >> 4;

    // ---- LN phase: thread (row = t>>4, cb = t&15) owns cols cb*8..+7 ----
    {
        int row = t >> 4, cb = t & 15;
        const float* rp = mI + ((size_t)bid * 16 + row) * 128 + cb * 8;
        float4 v0 = *(const float4*)(rp);
        float4 v1 = *(const float4*)(rp + 4);
        float s  = v0.x + v0.y + v0.z + v0.w + v1.x + v1.y + v1.z + v1.w;
        float ss = v0.x*v0.x + v0.y*v0.y + v0.z*v0.z + v0.w*v0.w
                 + v1.x*v1.x + v1.y*v1.y + v1.z*v1.z + v1.w*v1.w;
        #pragma unroll
        for (int off = 8; off > 0; off >>= 1) {
            s  += __shfl_xor(s, off);
            ss += __shfl_xor(ss, off);
        }
        float mean = s * (1.0f / 128.0f);
        float var  = ss * (1.0f / 128.0f) - mean * mean;
        float rstd = rsqrtf(var + 1e-5f);
        float4 wa = *(const float4*)(lnw + cb * 8);
        float4 wb = *(const float4*)(lnw + cb * 8 + 4);
        float4 ba = *(const float4*)(lnb + cb * 8);
        float4 bb = *(const float4*)(lnb + cb * 8 + 4);
        uint16_t y[8];
        y[0] = f2bf((v0.x - mean) * rstd * wa.x + ba.x);
        y[1] = f2bf((v0.y - mean) * rstd * wa.y + ba.y);
        y[2] = f2bf((v0.z - mean) * rstd * wa.z + ba.z);
        y[3] = f2bf((v0.w - mean) * rstd * wa.w + ba.w);
        y[4] = f2bf((v1.x - mean) * rstd * wb.x + bb.x);
        y[5] = f2bf((v1.y - mean) * rstd * wb.y + bb.y);
        y[6] = f2bf((v1.z - mean) * rstd * wb.z + bb.z);
        y[7] = f2bf((v1.w - mean) * rstd * wb.w + bb.w);
        int g = cb * 16 + (row ^ (cb & 7));           // swizzled granule
        *(uint2*)&mns[g * 8]     = *(uint2*)&y[0];
        *(uint2*)&mns[g * 8 + 4] = *(uint2*)&y[4];
    }
    __syncthreads();

    // ---- proj phase: wave w computes f-tile w (16 f) x 16 rows, K=128 ----
    const int w = t >> 6, l = t & 63;
    const int l16 = l & 15, lh = l >> 4;
    f32x4 acc = (f32x4)(0.0f);
    #pragma unroll
    for (int ks = 0; ks < 4; ++ks) {
        int cb = ks * 4 + lh;
        int g  = cb * 16 + (l16 ^ (cb & 7));
        short8 a = *(const short8*)&mns[g * 8];
        short8 b = *(const short8*)(W1f + (size_t)(w * 4 + ks) * 512 + l * 8);
        acc = __builtin_amdgcn_mfma_f32_16x16x32_bf16(a, b, acc, 0, 0, 0);
    }
    // C: col = l16 = f-local, rows = lh*4+v = i-local
    float b1v = b1[w * 16 + l16];
    uint16_t* dst = (w < 2) ? At : Bt;
    const int cch = w & 1;                       // cc = cch*16 + l16
    const int base2 = (r >> 5) * 512 + (l16 + 16 * ((r >> 3) & 3)) * 8 + (r & 7);
    #pragma unroll
    for (int v = 0; v < 4; ++v) {
        int i = i0 + lh * 4 + v;
        int mtile = i * 2 + cch;
        dst[(size_t)mtile * 2048 + base2] = f2bf(acc[v] + b1v);
    }
}

// ---------------- kernel 2: fused OPM GEMM + MFMA W2 epilogue (256x128 tile)
// Grid (64,32): block covers i in [by*8,by*8+8), j in [bx*4,bx*4+4). 512 thr, 8 waves.
// Main: C[256ic][128jd], wave (wm=w>>1, wn=w&1) does 64x64.
// LDS:  Out[p=32][kd stride 1032] bf16 (padded, dynamic 66KB), Out = C/128
// Epi:  Z[f=128][p=32]; wave w owns f-tile w, 2 p-tiles, 32 ks.
extern __shared__ uint16_t outl[];
__global__ __launch_bounds__(512, 4) void fused_opm(
    const uint16_t* __restrict__ At, const uint16_t* __restrict__ Bt,
    const uint16_t* __restrict__ W2f, const float* __restrict__ b2,
    float* __restrict__ z)
{
    const int t = threadIdx.x;
    const int w = t >> 6, l = t & 63;
    const int l16 = l & 15, lh = l >> 4;
    const int bx = blockIdx.x, by = blockIdx.y;
    const int wm = w >> 1, wn = w & 1;

    // ---- main GEMM: contiguous 1KB/wave fragment loads ----
    f32x4 acc[4][4];
    #pragma unroll
    for (int a = 0; a < 4; ++a)
        #pragma unroll
        for (int b = 0; b < 4; ++b) acc[a][b] = (f32x4)(0.0f);

    const uint16_t* Abase = At + (size_t)(by * 16 + wm * 4) * 4 * 512 + l * 8;
    const uint16_t* Bbase = Bt + (size_t)(bx * 8 + wn * 4) * 4 * 512 + l * 8;
    #pragma unroll
    for (int ks = 0; ks < 4; ++ks) {
        short8 af[4], bf[4];
        #pragma unroll
        for (int mt = 0; mt < 4; ++mt)
            af[mt] = *(const short8*)(Abase + (size_t)(mt * 4 + ks) * 512);
        #pragma unroll
        for (int nt = 0; nt < 4; ++nt)
            bf[nt] = *(const short8*)(Bbase + (size_t)(nt * 4 + ks) * 512);
        #pragma unroll
        for (int mt = 0; mt < 4; ++mt)
            #pragma unroll
            for (int nt = 0; nt < 4; ++nt)
                acc[mt][nt] = __builtin_amdgcn_mfma_f32_16x16x32_bf16(
                    af[mt], bf[nt], acc[mt][nt], 0, 0, 0);
    }

    // ---- C/128 -> bf16 -> Out_lds[p][kd] (stride 1032) ----
    // reg v of acc[mt][nt] = C[row = wm*64+mt*16+lh*4+v][col = wn*64+nt*16+l16]
    #pragma unroll
    for (int mt = 0; mt < 4; ++mt) {
        int pi = wm * 2 + (mt >> 1);
        int c0 = (mt & 1) * 16 + lh * 4;
        #pragma unroll
        for (int nt = 0; nt < 4; ++nt) {
            int pj = wn * 2 + (nt >> 1);
            int d  = (nt & 1) * 16 + l16;
            int p  = pi * 4 + pj;
            f32x4 v = acc[mt][nt];
            uint32_t u0 = (uint32_t)f2bf(v[0] * (1.0f / 128.0f)) |
                          ((uint32_t)f2bf(v[1] * (1.0f / 128.0f)) << 16);
            uint32_t u1 = (uint32_t)f2bf(v[2] * (1.0f / 128.0f)) |
                          ((uint32_t)f2bf(v[3] * (1.0f / 128.0f)) << 16);
            uint2 pk; pk.x = u0; pk.y = u1;
            *(uint2*)&outl[p * 1032 + d * 32 + c0] = pk;
        }
    }
    __syncthreads();

    // ---- epilogue: wave w = f-tile w; 2 p-tiles; 32 ks; W-frag prefetch ----
    f32x4 zacc[2][2];
    #pragma unroll
    for (int a = 0; a < 2; ++a) { zacc[a][0] = (f32x4)(0.0f); zacc[a][1] = (f32x4)(0.0f); }
    const uint16_t* Wt  = W2f + (size_t)w * 32 * 512 + l * 8;
    const uint16_t* Ob0 = &outl[l16 * 1032 + lh * 8];
    const uint16_t* Ob1 = &outl[(16 + l16) * 1032 + lh * 8];

    short8 cw = *(const short8*)(Wt);
    #pragma unroll 8
    for (int ks = 0; ks < 32; ++ks) {
        short8 nw;
        if (ks < 31) nw = *(const short8*)(Wt + (size_t)(ks + 1) * 512);
        short8 o0 = *(const short8*)(Ob0 + ks * 32);
        short8 o1 = *(const short8*)(Ob1 + ks * 32);
        zacc[0][ks & 1] = __builtin_amdgcn_mfma_f32_16x16x32_bf16(cw, o0, zacc[0][ks & 1], 0, 0, 0);
        zacc[1][ks & 1] = __builtin_amdgcn_mfma_f32_16x16x32_bf16(cw, o1, zacc[1][ks & 1], 0, 0, 0);
        cw = nw;
    }

    // ---- write z: lane p = pt*16+l16, rows f0 = w*16+lh*4 ----
    #pragma unroll
    for (int pt = 0; pt < 2; ++pt) {
        int p  = pt * 16 + l16;
        int zi = by * 8 + (p >> 2);
        int zj = bx * 4 + (p & 3);
        int f0 = w * 16 + lh * 4;
        float* zrow = z + ((size_t)zi * 256 + zj) * 128;
        float4 zr;
        zr.x = zacc[pt][0][0] + zacc[pt][1][0] + b2[f0 + 0];
        zr.y = zacc[pt][0][1] + zacc[pt][1][1] + b2[f0 + 1];
        zr.z = zacc[pt][0][2] + zacc[pt][1][2] + b2[f0 + 2];
        zr.w = zacc[pt][0][3] + zacc[pt][1][3] + b2[f0 + 3];
        *(float4*)(zrow + f0) = zr;
    }
}

extern "C" void kernel_launch(void* const* d_in, const int* in_sizes, int n_in,
                              void* d_out, int out_size, void* d_ws, size_t ws_size,
                              hipStream_t stream) {
    const float* m_in = (const float*)d_in[0];
    const float* ln_w = (const float*)d_in[1];
    const float* ln_b = (const float*)d_in[2];
    const float* W1   = (const float*)d_in[3];
    const float* b1   = (const float*)d_in[4];
    const float* W2   = (const float*)d_in[5];
    const float* b2   = (const float*)d_in[6];
    float* z = (float*)d_out;

    uint16_t* At  = (uint16_t*)d_ws;                 // 2 MB
    uint16_t* Bt  = At + 8192 * 128;                 // 2 MB
    uint16_t* W2f = Bt + 8192 * 128;                 // 256 KB
    uint16_t* W1f = W2f + 128 * 1024;                // 16 KB

    prep_weights<<<544, 256, 0, stream>>>(W2, W1, W2f, W1f);
    ln_proj<<<2048, 256, 0, stream>>>(m_in, ln_w, ln_b, W1f, b1, At, Bt);
    fused_opm<<<dim3(64, 32), 512, 32 * 1032 * 2, stream>>>(At, Bt, W2f, b2, z);
}

// Round 8
// 66.199 us; speedup vs baseline: 15.2417x; 1.0872x over previous
//
#include <hip/hip_runtime.h>
#include <stdint.h>

typedef __attribute__((ext_vector_type(8))) short  short8;
typedef __attribute__((ext_vector_type(4))) float  f32x4;

static __device__ __forceinline__ uint16_t f2bf(float x) {
    union { float f; uint32_t u; } v; v.f = x;
    return (uint16_t)((v.u + 0x7FFFu + ((v.u >> 16) & 1u)) >> 16);
}

// Fragment-order layout for a 16x32 bf16 MFMA operand tile:
//   frag[(tile*NKS + ks)*512 + lane*8 + e]  where lane = row16 + 16*kh, k = ks*32 + kh*8 + e

// ---------------- kernel 0: weights prep
__global__ __launch_bounds__(256) void prep_weights(
    const float* __restrict__ W2, const float* __restrict__ W1,
    uint16_t* __restrict__ W2f, uint16_t* __restrict__ W1f) {
    int bid = blockIdx.x, t = threadIdx.x;
    if (bid < 512) {
        int idx = bid * 256 + t;              // 0..131071
        int f  = idx >> 10;
        int kd = idx & 1023;
        int d = kd >> 5, c = kd & 31;
        int ftile = f >> 4, l16 = f & 15;
        int ks = kd >> 5, kh = (kd >> 3) & 3, e = kd & 7;
        W2f[(size_t)(ftile * 32 + ks) * 512 + (l16 + 16 * kh) * 8 + e] =
            f2bf(W2[f * 1024 + c * 32 + d]);
    } else {
        int idx = (bid - 512) * 256 + t;      // 0..8191
        int f = idx >> 7, c = idx & 127;
        int ftile = f >> 4, l16 = f & 15;
        int ks = c >> 5, kh = (c >> 3) & 3, e = c & 7;
        W1f[(size_t)(ftile * 4 + ks) * 512 + (l16 + 16 * kh) * 8 + e] =
            f2bf(W1[f * 128 + c]);
    }
}

// ---------------- kernel 1: LayerNorm + proj via MFMA -> At/Bt fragment order
__global__ __launch_bounds__(256) void ln_proj(
    const float* __restrict__ mI, const float* __restrict__ lnw,
    const float* __restrict__ lnb, const uint16_t* __restrict__ W1f,
    const float* __restrict__ b1,
    uint16_t* __restrict__ At, uint16_t* __restrict__ Bt)
{
    __shared__ __align__(16) uint16_t mns[256 * 8];   // 4 KB, granule-swizzled
    const int t = threadIdx.x;
    const int bid = blockIdx.x;
    const int i0 = (bid * 16) & 255;
    const int r  = bid >> 4;

    {
        int row = t >> 4, cb = t & 15;
        const float* rp = mI + ((size_t)bid * 16 + row) * 128 + cb * 8;
        float4 v0 = *(const float4*)(rp);
        float4 v1 = *(const float4*)(rp + 4);
        float s  = v0.x + v0.y + v0.z + v0.w + v1.x + v1.y + v1.z + v1.w;
        float ss = v0.x*v0.x + v0.y*v0.y + v0.z*v0.z + v0.w*v0.w
                 + v1.x*v1.x + v1.y*v1.y + v1.z*v1.z + v1.w*v1.w;
        #pragma unroll
        for (int off = 8; off > 0; off >>= 1) {
            s  += __shfl_xor(s, off);
            ss += __shfl_xor(ss, off);
        }
        float mean = s * (1.0f / 128.0f);
        float var  = ss * (1.0f / 128.0f) - mean * mean;
        float rstd = rsqrtf(var + 1e-5f);
        float4 wa = *(const float4*)(lnw + cb * 8);
        float4 wb = *(const float4*)(lnw + cb * 8 + 4);
        float4 ba = *(const float4*)(lnb + cb * 8);
        float4 bb = *(const float4*)(lnb + cb * 8 + 4);
        uint16_t y[8];
        y[0] = f2bf((v0.x - mean) * rstd * wa.x + ba.x);
        y[1] = f2bf((v0.y - mean) * rstd * wa.y + ba.y);
        y[2] = f2bf((v0.z - mean) * rstd * wa.z + ba.z);
        y[3] = f2bf((v0.w - mean) * rstd * wa.w + ba.w);
        y[4] = f2bf((v1.x - mean) * rstd * wb.x + bb.x);
        y[5] = f2bf((v1.y - mean) * rstd * wb.y + bb.y);
        y[6] = f2bf((v1.z - mean) * rstd * wb.z + bb.z);
        y[7] = f2bf((v1.w - mean) * rstd * wb.w + bb.w);
        int g = cb * 16 + (row ^ (cb & 7));           // swizzled granule
        *(uint2*)&mns[g * 8]     = *(uint2*)&y[0];
        *(uint2*)&mns[g * 8 + 4] = *(uint2*)&y[4];
    }
    __syncthreads();

    const int w = t >> 6, l = t & 63;
    const int l16 = l & 15, lh = l >> 4;
    f32x4 acc = (f32x4)(0.0f);
    #pragma unroll
    for (int ks = 0; ks < 4; ++ks) {
        int cb = ks * 4 + lh;
        int g  = cb * 16 + (l16 ^ (cb & 7));
        short8 a = *(const short8*)&mns[g * 8];
        short8 b = *(const short8*)(W1f + (size_t)(w * 4 + ks) * 512 + l * 8);
        acc = __builtin_amdgcn_mfma_f32_16x16x32_bf16(a, b, acc, 0, 0, 0);
    }
    float b1v = b1[w * 16 + l16];
    uint16_t* dst = (w < 2) ? At : Bt;
    const int cch = w & 1;
    const int base2 = (r >> 5) * 512 + (l16 + 16 * ((r >> 3) & 3)) * 8 + (r & 7);
    #pragma unroll
    for (int v = 0; v < 4; ++v) {
        int i = i0 + lh * 4 + v;
        int mtile = i * 2 + cch;
        dst[(size_t)mtile * 2048 + base2] = f2bf(acc[v] + b1v);
    }
}

// ---------------- kernel 2: fused OPM GEMM + MFMA W2 epilogue (256x128 tile)
// Grid (64,32). 512 thr, 8 waves. Main: C[256ic][128jd], wave (wm,wn) does 64x64.
// LDS:  Out in FRAGMENT ORDER [pt=2][ks=32][lane*8] bf16, ks-XOR swizzled (64 KB dynamic)
// Epi:  Z[f=128][p=32]; wave w owns f-tile w, 2 p-tiles, 32 ks.
extern __shared__ uint16_t outl[];
__global__ __launch_bounds__(512, 4) void fused_opm(
    const uint16_t* __restrict__ At, const uint16_t* __restrict__ Bt,
    const uint16_t* __restrict__ W2f, const float* __restrict__ b2,
    float* __restrict__ z)
{
    const int t = threadIdx.x;
    const int w = t >> 6, l = t & 63;
    const int l16 = l & 15, lh = l >> 4;
    const int bx = blockIdx.x, by = blockIdx.y;
    const int wm = w >> 1, wn = w & 1;

    // ---- main GEMM: contiguous 1KB/wave fragment loads ----
    f32x4 acc[4][4];
    #pragma unroll
    for (int a = 0; a < 4; ++a)
        #pragma unroll
        for (int b = 0; b < 4; ++b) acc[a][b] = (f32x4)(0.0f);

    const uint16_t* Abase = At + (size_t)(by * 16 + wm * 4) * 4 * 512 + l * 8;
    const uint16_t* Bbase = Bt + (size_t)(bx * 8 + wn * 4) * 4 * 512 + l * 8;
    #pragma unroll
    for (int ks = 0; ks < 4; ++ks) {
        short8 af[4], bf[4];
        #pragma unroll
        for (int mt = 0; mt < 4; ++mt)
            af[mt] = *(const short8*)(Abase + (size_t)(mt * 4 + ks) * 512);
        #pragma unroll
        for (int nt = 0; nt < 4; ++nt)
            bf[nt] = *(const short8*)(Bbase + (size_t)(nt * 4 + ks) * 512);
        #pragma unroll
        for (int mt = 0; mt < 4; ++mt)
            #pragma unroll
            for (int nt = 0; nt < 4; ++nt)
                acc[mt][nt] = __builtin_amdgcn_mfma_f32_16x16x32_bf16(
                    af[mt], bf[nt], acc[mt][nt], 0, 0, 0);
    }

    // ---- C/128 -> bf16 -> Out LDS in fragment order, ks-XOR swizzled ----
    // acc[mt][nt] reg v = C[ic = wm*64+mt*16+lh*4+v][jd = wn*64+nt*16+l16]
    // p = ic>>5*4 + jd>>5; c = ic&31; d = jd&31; kd = d*32+c
    // frag: ks = d; kh = c>>3 = (mt&1)*2 + (lh>>1); e = c&7 = (lh&1)*4 + v
    #pragma unroll
    for (int mt = 0; mt < 4; ++mt) {
        const int kh = (mt & 1) * 2 + (lh >> 1);
        const int e0 = (lh & 1) * 4;
        #pragma unroll
        for (int nt = 0; nt < 4; ++nt) {
            int p  = wm * 8 + (mt >> 1) * 4 + wn * 2 + (nt >> 1);
            int ks = (nt & 1) * 16 + l16;
            int pt = p >> 4, l16t = p & 15;
            f32x4 v = acc[mt][nt];
            uint32_t u0 = (uint32_t)f2bf(v[0] * (1.0f / 128.0f)) |
                          ((uint32_t)f2bf(v[1] * (1.0f / 128.0f)) << 16);
            uint32_t u1 = (uint32_t)f2bf(v[2] * (1.0f / 128.0f)) |
                          ((uint32_t)f2bf(v[3] * (1.0f / 128.0f)) << 16);
            uint32_t byte = (uint32_t)(pt * 32 + ks) * 1024u
                          + (uint32_t)(l16t + 16 * kh) * 16u + (uint32_t)e0 * 2u;
            byte ^= (uint32_t)(ks & 7) << 4;
            uint2 pk; pk.x = u0; pk.y = u1;
            *(uint2*)((char*)outl + byte) = pk;
        }
    }
    __syncthreads();

    // ---- epilogue: wave w = f-tile w; 2 p-tiles; 32 ks; W-frag prefetch ----
    f32x4 zacc[2][2];
    #pragma unroll
    for (int a = 0; a < 2; ++a) { zacc[a][0] = (f32x4)(0.0f); zacc[a][1] = (f32x4)(0.0f); }
    const uint16_t* Wt = W2f + (size_t)w * 32 * 512 + l * 8;

    short8 cw = *(const short8*)(Wt);
    #pragma unroll 8
    for (int ks = 0; ks < 32; ++ks) {
        short8 nw;
        if (ks < 31) nw = *(const short8*)(Wt + (size_t)(ks + 1) * 512);
        uint32_t swz = (uint32_t)(ks & 7) << 4;
        uint32_t b0 = ((uint32_t)ks * 1024u + (uint32_t)l * 16u) ^ swz;
        uint32_t b1 = ((uint32_t)(32 + ks) * 1024u + (uint32_t)l * 16u) ^ swz;
        short8 o0 = *(const short8*)((const char*)outl + b0);
        short8 o1 = *(const short8*)((const char*)outl + b1);
        zacc[0][ks & 1] = __builtin_amdgcn_mfma_f32_16x16x32_bf16(cw, o0, zacc[0][ks & 1], 0, 0, 0);
        zacc[1][ks & 1] = __builtin_amdgcn_mfma_f32_16x16x32_bf16(cw, o1, zacc[1][ks & 1], 0, 0, 0);
        cw = nw;
    }

    // ---- write z: lane p = pt*16+l16, rows f0 = w*16+lh*4 ----
    #pragma unroll
    for (int pt = 0; pt < 2; ++pt) {
        int p  = pt * 16 + l16;
        int zi = by * 8 + (p >> 2);
        int zj = bx * 4 + (p & 3);
        int f0 = w * 16 + lh * 4;
        float* zrow = z + ((size_t)zi * 256 + zj) * 128;
        float4 zr;
        zr.x = zacc[pt][0][0] + zacc[pt][1][0] + b2[f0 + 0];
        zr.y = zacc[pt][0][1] + zacc[pt][1][1] + b2[f0 + 1];
        zr.z = zacc[pt][0][2] + zacc[pt][1][2] + b2[f0 + 2];
        zr.w = zacc[pt][0][3] + zacc[pt][1][3] + b2[f0 + 3];
        *(float4*)(zrow + f0) = zr;
    }
}

extern "C" void kernel_launch(void* const* d_in, const int* in_sizes, int n_in,
                              void* d_out, int out_size, void* d_ws, size_t ws_size,
                              hipStream_t stream) {
    const float* m_in = (const float*)d_in[0];
    const float* ln_w = (const float*)d_in[1];
    const float* ln_b = (const float*)d_in[2];
    const float* W1   = (const float*)d_in[3];
    const float* b1   = (const float*)d_in[4];
    const float* W2   = (const float*)d_in[5];
    const float* b2   = (const float*)d_in[6];
    float* z = (float*)d_out;

    uint16_t* At  = (uint16_t*)d_ws;                 // 2 MB
    uint16_t* Bt  = At + 8192 * 128;                 // 2 MB
    uint16_t* W2f = Bt + 8192 * 128;                 // 256 KB
    uint16_t* W1f = W2f + 128 * 1024;                // 16 KB

    prep_weights<<<544, 256, 0, stream>>>(W2, W1, W2f, W1f);
    ln_proj<<<2048, 256, 0, stream>>>(m_in, ln_w, ln_b, W1f, b1, At, Bt);
    fused_opm<<<dim3(64, 32), 512, 64 * 1024, stream>>>(At, Bt, W2f, b2, z);
}

// Round 10
// 64.155 us; speedup vs baseline: 15.7272x; 1.0319x over previous
//
#include <hip/hip_runtime.h>
#include <stdint.h>

typedef __attribute__((ext_vector_type(8))) short  short8;
typedef __attribute__((ext_vector_type(4))) float  f32x4;

static __device__ __forceinline__ uint16_t f2bf(float x) {
    union { float f; uint32_t u; } v; v.f = x;
    return (uint16_t)((v.u + 0x7FFFu + ((v.u >> 16) & 1u)) >> 16);
}

// Fragment-order layout for a 16x32 bf16 MFMA operand tile:
//   frag[(tile*NKS + ks)*512 + lane*8 + e]  where lane = row16 + 16*kh, k = ks*32 + kh*8 + e

// ---------------- kernel 0: weights prep
__global__ __launch_bounds__(256) void prep_weights(
    const float* __restrict__ W2, const float* __restrict__ W1,
    uint16_t* __restrict__ W2f, uint16_t* __restrict__ W1f) {
    int bid = blockIdx.x, t = threadIdx.x;
    if (bid < 512) {
        int idx = bid * 256 + t;              // 0..131071
        int f  = idx >> 10;
        int kd = idx & 1023;
        int d = kd >> 5, c = kd & 31;
        int ftile = f >> 4, l16 = f & 15;
        int ks = kd >> 5, kh = (kd >> 3) & 3, e = kd & 7;
        W2f[(size_t)(ftile * 32 + ks) * 512 + (l16 + 16 * kh) * 8 + e] =
            f2bf(W2[f * 1024 + c * 32 + d]);
    } else {
        int idx = (bid - 512) * 256 + t;      // 0..8191
        int f = idx >> 7, c = idx & 127;
        int ftile = f >> 4, l16 = f & 15;
        int ks = c >> 5, kh = (c >> 3) & 3, e = c & 7;
        W1f[(size_t)(ftile * 4 + ks) * 512 + (l16 + 16 * kh) * 8 + e] =
            f2bf(W1[f * 128 + c]);
    }
}

// ---------------- kernel 1: LayerNorm + proj via MFMA -> At/Bt fragment order
// At carries proj/128 (OPM scale folded in); Bt carries raw proj.
__global__ __launch_bounds__(256) void ln_proj(
    const float* __restrict__ mI, const float* __restrict__ lnw,
    const float* __restrict__ lnb, const uint16_t* __restrict__ W1f,
    const float* __restrict__ b1,
    uint16_t* __restrict__ At, uint16_t* __restrict__ Bt)
{
    __shared__ __align__(16) uint16_t mns[256 * 8];   // 4 KB, granule-swizzled
    const int t = threadIdx.x;
    const int bid = blockIdx.x;
    const int i0 = (bid * 16) & 255;
    const int r  = bid >> 4;

    {
        int row = t >> 4, cb = t & 15;
        const float* rp = mI + ((size_t)bid * 16 + row) * 128 + cb * 8;
        float4 v0 = *(const float4*)(rp);
        float4 v1 = *(const float4*)(rp + 4);
        float s  = v0.x + v0.y + v0.z + v0.w + v1.x + v1.y + v1.z + v1.w;
        float ss = v0.x*v0.x + v0.y*v0.y + v0.z*v0.z + v0.w*v0.w
                 + v1.x*v1.x + v1.y*v1.y + v1.z*v1.z + v1.w*v1.w;
        #pragma unroll
        for (int off = 8; off > 0; off >>= 1) {
            s  += __shfl_xor(s, off);
            ss += __shfl_xor(ss, off);
        }
        float mean = s * (1.0f / 128.0f);
        float var  = ss * (1.0f / 128.0f) - mean * mean;
        float rstd = rsqrtf(var + 1e-5f);
        float4 wa = *(const float4*)(lnw + cb * 8);
        float4 wb = *(const float4*)(lnw + cb * 8 + 4);
        float4 ba = *(const float4*)(lnb + cb * 8);
        float4 bb = *(const float4*)(lnb + cb * 8 + 4);
        uint16_t y[8];
        y[0] = f2bf((v0.x - mean) * rstd * wa.x + ba.x);
        y[1] = f2bf((v0.y - mean) * rstd * wa.y + ba.y);
        y[2] = f2bf((v0.z - mean) * rstd * wa.z + ba.z);
        y[3] = f2bf((v0.w - mean) * rstd * wa.w + ba.w);
        y[4] = f2bf((v1.x - mean) * rstd * wb.x + bb.x);
        y[5] = f2bf((v1.y - mean) * rstd * wb.y + bb.y);
        y[6] = f2bf((v1.z - mean) * rstd * wb.z + bb.z);
        y[7] = f2bf((v1.w - mean) * rstd * wb.w + bb.w);
        int g = cb * 16 + (row ^ (cb & 7));           // swizzled granule
        *(uint2*)&mns[g * 8]     = *(uint2*)&y[0];
        *(uint2*)&mns[g * 8 + 4] = *(uint2*)&y[4];
    }
    __syncthreads();

    const int w = t >> 6, l = t & 63;
    const int l16 = l & 15, lh = l >> 4;
    f32x4 acc = (f32x4)(0.0f);
    #pragma unroll
    for (int ks = 0; ks < 4; ++ks) {
        int cb = ks * 4 + lh;
        int g  = cb * 16 + (l16 ^ (cb & 7));
        short8 a = *(const short8*)&mns[g * 8];
        short8 b = *(const short8*)(W1f + (size_t)(w * 4 + ks) * 512 + l * 8);
        acc = __builtin_amdgcn_mfma_f32_16x16x32_bf16(a, b, acc, 0, 0, 0);
    }
    float b1v = b1[w * 16 + l16];
    uint16_t* dst = (w < 2) ? At : Bt;
    const float scale = (w < 2) ? (1.0f / 128.0f) : 1.0f;   // fold OPM /128 into At
    const int cch = w & 1;
    const int base2 = (r >> 5) * 512 + (l16 + 16 * ((r >> 3) & 3)) * 8 + (r & 7);
    #pragma unroll
    for (int v = 0; v < 4; ++v) {
        int i = i0 + lh * 4 + v;
        int mtile = i * 2 + cch;
        dst[(size_t)mtile * 2048 + base2] = f2bf((acc[v] + b1v) * scale);
    }
}

// ---------------- kernel 2: fused OPM GEMM + MFMA W2 epilogue (256x128 tile)
// Grid (64,32). 512 thr, 8 waves. Main: C[256ic][128jd], wave (wm,wn) does 64x64.
// LDS:  Out in FRAGMENT ORDER [pt=2][ks=32][lane*8] bf16, ks-XOR swizzled (64 KB dynamic)
// Epi:  Z[f=128][p=32]; wave w owns f-tile w, 2 p-tiles, 32 ks, W-prefetch depth 4.
extern __shared__ uint16_t outl[];
__global__ __launch_bounds__(512, 4) void fused_opm(
    const uint16_t* __restrict__ At, const uint16_t* __restrict__ Bt,
    const uint16_t* __restrict__ W2f, const float* __restrict__ b2,
    float* __restrict__ z)
{
    const int t = threadIdx.x;
    const int w = t >> 6, l = t & 63;
    const int l16 = l & 15, lh = l >> 4;
    const int bx = blockIdx.x, by = blockIdx.y;
    const int wm = w >> 1, wn = w & 1;

    // ---- main GEMM: contiguous 1KB/wave fragment loads ----
    f32x4 acc[4][4];
    #pragma unroll
    for (int a = 0; a < 4; ++a)
        #pragma unroll
        for (int b = 0; b < 4; ++b) acc[a][b] = (f32x4)(0.0f);

    const uint16_t* Abase = At + (size_t)(by * 16 + wm * 4) * 4 * 512 + l * 8;
    const uint16_t* Bbase = Bt + (size_t)(bx * 8 + wn * 4) * 4 * 512 + l * 8;
    #pragma unroll
    for (int ks = 0; ks < 4; ++ks) {
        short8 af[4], bf[4];
        #pragma unroll
        for (int mt = 0; mt < 4; ++mt)
            af[mt] = *(const short8*)(Abase + (size_t)(mt * 4 + ks) * 512);
        #pragma unroll
        for (int nt = 0; nt < 4; ++nt)
            bf[nt] = *(const short8*)(Bbase + (size_t)(nt * 4 + ks) * 512);
        #pragma unroll
        for (int mt = 0; mt < 4; ++mt)
            #pragma unroll
            for (int nt = 0; nt < 4; ++nt)
                acc[mt][nt] = __builtin_amdgcn_mfma_f32_16x16x32_bf16(
                    af[mt], bf[nt], acc[mt][nt], 0, 0, 0);
    }

    // ---- issue first 4 epilogue W-frag loads NOW (latency hides under C-write) ----
    const uint16_t* Wt = W2f + (size_t)w * 32 * 512 + l * 8;
    short8 wb[4];
    #pragma unroll
    for (int q = 0; q < 4; ++q)
        wb[q] = *(const short8*)(Wt + (size_t)q * 512);

    // ---- C (pre-scaled by 1/128 via At) -> bf16 -> Out LDS frag-order, ks-XOR swz ----
    // acc[mt][nt] reg v = C[ic = wm*64+mt*16+lh*4+v][jd = wn*64+nt*16+l16]
    // frag: ks = d; kh = (mt&1)*2+(lh>>1); e = (lh&1)*4 + v
    #pragma unroll
    for (int mt = 0; mt < 4; ++mt) {
        const int kh = (mt & 1) * 2 + (lh >> 1);
        const int e0 = (lh & 1) * 4;
        #pragma unroll
        for (int nt = 0; nt < 4; ++nt) {
            int p  = wm * 8 + (mt >> 1) * 4 + wn * 2 + (nt >> 1);
            int ks = (nt & 1) * 16 + l16;
            int pt = p >> 4, l16t = p & 15;
            f32x4 v = acc[mt][nt];
            uint32_t u0 = (uint32_t)f2bf(v[0]) | ((uint32_t)f2bf(v[1]) << 16);
            uint32_t u1 = (uint32_t)f2bf(v[2]) | ((uint32_t)f2bf(v[3]) << 16);
            uint32_t byte = (uint32_t)(pt * 32 + ks) * 1024u
                          + (uint32_t)(l16t + 16 * kh) * 16u + (uint32_t)e0 * 2u;
            byte ^= (uint32_t)(ks & 7) << 4;
            uint2 pk; pk.x = u0; pk.y = u1;
            *(uint2*)((char*)outl + byte) = pk;
        }
    }
    __syncthreads();

    // ---- epilogue: wave w = f-tile w; 2 p-tiles; 32 ks; prefetch depth 4 ----
    f32x4 zacc[2][2];
    #pragma unroll
    for (int a = 0; a < 2; ++a) { zacc[a][0] = (f32x4)(0.0f); zacc[a][1] = (f32x4)(0.0f); }

    #pragma unroll
    for (int ks = 0; ks < 32; ++ks) {
        short8 cw = wb[ks & 3];
        if (ks < 28) wb[ks & 3] = *(const short8*)(Wt + (size_t)(ks + 4) * 512);
        uint32_t swz = (uint32_t)(ks & 7) << 4;
        uint32_t o0b = ((uint32_t)ks * 1024u + (uint32_t)l * 16u) ^ swz;
        uint32_t o1b = ((uint32_t)(32 + ks) * 1024u + (uint32_t)l * 16u) ^ swz;
        short8 o0 = *(const short8*)((const char*)outl + o0b);
        short8 o1 = *(const short8*)((const char*)outl + o1b);
        zacc[0][ks & 1] = __builtin_amdgcn_mfma_f32_16x16x32_bf16(cw, o0, zacc[0][ks & 1], 0, 0, 0);
        zacc[1][ks & 1] = __builtin_amdgcn_mfma_f32_16x16x32_bf16(cw, o1, zacc[1][ks & 1], 0, 0, 0);
    }

    // ---- write z: lane p = pt*16+l16, rows f0 = w*16+lh*4 ----
    const int f0 = w * 16 + lh * 4;
    const float4 bv = *(const float4*)(b2 + f0);
    #pragma unroll
    for (int pt = 0; pt < 2; ++pt) {
        int p  = pt * 16 + l16;
        int zi = by * 8 + (p >> 2);
        int zj = bx * 4 + (p & 3);
        float* zrow = z + ((size_t)zi * 256 + zj) * 128;
        float4 zr;
        zr.x = zacc[pt][0][0] + zacc[pt][1][0] + bv.x;
        zr.y = zacc[pt][0][1] + zacc[pt][1][1] + bv.y;
        zr.z = zacc[pt][0][2] + zacc[pt][1][2] + bv.z;
        zr.w = zacc[pt][0][3] + zacc[pt][1][3] + bv.w;
        *(float4*)(zrow + f0) = zr;
    }
}

extern "C" void kernel_launch(void* const* d_in, const int* in_sizes, int n_in,
                              void* d_out, int out_size, void* d_ws, size_t ws_size,
                              hipStream_t stream) {
    const float* m_in = (const float*)d_in[0];
    const float* ln_w = (const float*)d_in[1];
    const float* ln_b = (const float*)d_in[2];
    const float* W1   = (const float*)d_in[3];
    const float* b1   = (const float*)d_in[4];
    const float* W2   = (const float*)d_in[5];
    const float* b2   = (const float*)d_in[6];
    float* z = (float*)d_out;

    uint16_t* At  = (uint16_t*)d_ws;                 // 2 MB
    uint16_t* Bt  = At + 8192 * 128;                 // 2 MB
    uint16_t* W2f = Bt + 8192 * 128;                 // 256 KB
    uint16_t* W1f = W2f + 128 * 1024;                // 16 KB

    prep_weights<<<544, 256, 0, stream>>>(W2, W1, W2f, W1f);
    ln_proj<<<2048, 256, 0, stream>>>(m_in, ln_w, ln_b, W1f, b1, At, Bt);
    fused_opm<<<dim3(64, 32), 512, 64 * 1024, stream>>>(At, Bt, W2f, b2, z);
}